// Round 1
// baseline (2879.927 us; speedup 1.0000x reference)
//
#include <hip/hip_runtime.h>
#include <math.h>

// Problem constants (from reference): N nodes, E edges, D features.
constexpr int NN = 100000;
constexpr int NE = 1600000;
constexpr int D  = 128;
constexpr float SLOPE = 0.2f;

// ---------------------------------------------------------------------------
// GEMM: h[N,128] = x[N,128] @ W[128,128], fp32 vector ALU (no fp32 MFMA on CDNA4).
// 64 rows x 64 cols per block (grid.y=2 covers the 128 cols), 256 threads.
// LDS: xsT (x-tile transposed, k-major, XOR-swizzled rows for conflict-free
// b128 reads) + Ws (W-tile, natural k-major). Exactly 64 KiB -> 2 blocks/CU.
// Inner loop per k: one ds_read_b128 from each tile -> 16 FMAs per lane.
// ---------------------------------------------------------------------------
__global__ __launch_bounds__(256) void gemm_xw(const float* __restrict__ x,
                                               const float* __restrict__ W,
                                               float* __restrict__ h) {
    __shared__ float xsT[128 * 64]; // xsT[k*64 + (r ^ ((k>>2)&7)<<2)] = x[rbase+r][k]
    __shared__ float Ws [128 * 64]; // Ws[k*64 + c] = W[k][cbase+c]
    const int tid   = threadIdx.x;
    const int rbase = blockIdx.x * 64;
    const int cbase = blockIdx.y * 64;

    // Stage W tile (coalesced float4, 2-way LDS bank alias = free).
#pragma unroll
    for (int i = 0; i < 8; ++i) {
        const int f = tid + i * 256;        // 0..2047
        const int k = f >> 4;               // 0..127
        const int c = (f & 15) << 2;        // 0..60
        const float4 w = *reinterpret_cast<const float4*>(W + k * D + cbase + c);
        *reinterpret_cast<float4*>(Ws + k * 64 + c) = w;
    }
    // Stage x tile transposed; swizzle row index by k-block to kill the
    // 32-way store conflict (down to ~4-way) while keeping reads conflict-free.
#pragma unroll
    for (int i = 0; i < 8; ++i) {
        const int f  = tid + i * 256;       // 0..2047
        const int r  = f >> 5;              // 0..63
        const int c4 = f & 31;              // float4 index along k
        const int k0 = c4 << 2;
        float4 v = make_float4(0.f, 0.f, 0.f, 0.f);
        const int row = rbase + r;
        if (row < NN) v = *reinterpret_cast<const float4*>(x + (size_t)row * D + k0);
        const int rs = r ^ ((c4 & 7) << 2); // swizzle: k0>>2 == c4
        xsT[(k0 + 0) * 64 + rs] = v.x;
        xsT[(k0 + 1) * 64 + rs] = v.y;
        xsT[(k0 + 2) * 64 + rs] = v.z;
        xsT[(k0 + 3) * 64 + rs] = v.w;
    }
    __syncthreads();

    const int r0 = (tid >> 4) << 2;         // 4 rows per thread
    const int c0 = (tid & 15) << 2;         // 4 cols per thread
    float acc[4][4] = {};
#pragma unroll 4
    for (int k = 0; k < 128; ++k) {
        const int sk = ((k >> 2) & 7) << 2;
        // (r0+i)^sk == (r0^sk)+i for i<4 (sk has no low-2 bits) -> b128 valid.
        const float4 xv = *reinterpret_cast<const float4*>(xsT + k * 64 + (r0 ^ sk));
        const float4 wv = *reinterpret_cast<const float4*>(Ws  + k * 64 + c0);
        const float xr[4] = {xv.x, xv.y, xv.z, xv.w};
        const float wr[4] = {wv.x, wv.y, wv.z, wv.w};
#pragma unroll
        for (int i = 0; i < 4; ++i)
#pragma unroll
            for (int j = 0; j < 4; ++j)
                acc[i][j] = fmaf(xr[i], wr[j], acc[i][j]);
    }

#pragma unroll
    for (int i = 0; i < 4; ++i) {
        const int row = rbase + r0 + i;
        if (row < NN) {
            const float4 o = make_float4(acc[i][0], acc[i][1], acc[i][2], acc[i][3]);
            *reinterpret_cast<float4*>(h + (size_t)row * D + cbase + c0) = o;
        }
    }
}

// ---------------------------------------------------------------------------
// s[i] = h[i,:] . a1 ; t[i] = h[i,:] . a2. One wave (64 lanes) per row,
// float2 per lane, butterfly shuffle reduce. HBM-bound (51 MB).
// ---------------------------------------------------------------------------
__global__ __launch_bounds__(256) void st_kernel(const float* __restrict__ h,
                                                 const float* __restrict__ a,
                                                 float* __restrict__ s,
                                                 float* __restrict__ t) {
    const int row  = (int)((blockIdx.x * 256 + threadIdx.x) >> 6);
    const int lane = threadIdx.x & 63;
    if (row >= NN) return;
    const float2 hv = *reinterpret_cast<const float2*>(h + (size_t)row * D + lane * 2);
    const float2 a1 = *reinterpret_cast<const float2*>(a + lane * 2);
    const float2 a2 = *reinterpret_cast<const float2*>(a + D + lane * 2);
    float sp = hv.x * a1.x + hv.y * a1.y;
    float tp = hv.x * a2.x + hv.y * a2.y;
#pragma unroll
    for (int off = 32; off > 0; off >>= 1) {
        sp += __shfl_xor(sp, off);
        tp += __shfl_xor(tp, off);
    }
    if (lane == 0) { s[row] = sp; t[row] = tp; }
}

// ---------------------------------------------------------------------------
// Per edge: ee = exp(-leaky_relu(s[src]+t[dst])); write ee; scatter-add
// ee * h[dst,:] into hp[src,:]. 32 lanes per edge, float4 per lane,
// hw fp32 atomics (agent scope, no CAS).
// ---------------------------------------------------------------------------
__global__ __launch_bounds__(256) void edge_scatter(const int* __restrict__ edge,
                                                    const float* __restrict__ h,
                                                    const float* __restrict__ s,
                                                    const float* __restrict__ t,
                                                    float* __restrict__ hp,
                                                    float* __restrict__ ee_out) {
    const int e    = blockIdx.x * 8 + (threadIdx.x >> 5);
    const int lane = threadIdx.x & 31;
    const int src  = edge[e];          // row 0 of edge[2,E]
    const int dst  = edge[NE + e];     // row 1
    const float es = s[src] + t[dst];
    const float lr = es > 0.f ? es : SLOPE * es;  // == leaky_relu (equal at 0)
    const float ee = expf(-lr);
    if (lane == 0) ee_out[e] = ee;
    const float4 hv = *reinterpret_cast<const float4*>(h + (size_t)dst * D + lane * 4);
    float* p = hp + (size_t)src * D + lane * 4;
    __hip_atomic_fetch_add(p + 0, ee * hv.x, __ATOMIC_RELAXED, __HIP_MEMORY_SCOPE_AGENT);
    __hip_atomic_fetch_add(p + 1, ee * hv.y, __ATOMIC_RELAXED, __HIP_MEMORY_SCOPE_AGENT);
    __hip_atomic_fetch_add(p + 2, ee * hv.z, __ATOMIC_RELAXED, __HIP_MEMORY_SCOPE_AGENT);
    __hip_atomic_fetch_add(p + 3, ee * hv.w, __ATOMIC_RELAXED, __HIP_MEMORY_SCOPE_AGENT);
}

// ---------------------------------------------------------------------------
// ELU in place over the accumulated h' region of d_out.
// ---------------------------------------------------------------------------
__global__ __launch_bounds__(256) void elu_kernel(float* __restrict__ hp) {
    const int i = blockIdx.x * 256 + threadIdx.x;  // float4 index, exact grid
    float4 v = reinterpret_cast<float4*>(hp)[i];
    v.x = v.x > 0.f ? v.x : expm1f(v.x);
    v.y = v.y > 0.f ? v.y : expm1f(v.y);
    v.z = v.z > 0.f ? v.z : expm1f(v.z);
    v.w = v.w > 0.f ? v.w : expm1f(v.w);
    reinterpret_cast<float4*>(hp)[i] = v;
}

extern "C" void kernel_launch(void* const* d_in, const int* in_sizes, int n_in,
                              void* d_out, int out_size, void* d_ws, size_t ws_size,
                              hipStream_t stream) {
    const int*   edge = (const int*)d_in[0];   // [2,E] int32
    const float* x    = (const float*)d_in[1]; // [N,128]
    const float* W    = (const float*)d_in[2]; // [128,128]
    const float* a    = (const float*)d_in[3]; // [1,256]

    float* out_hp = (float*)d_out;                        // elu(h') [N,128]
    float* out_ee = (float*)d_out + (size_t)NN * D;       // edge_e [E]

    // Workspace: h [N,128] (51.2 MB) + s[N] + t[N] (0.8 MB). ws is re-poisoned
    // 0xAA each call; every byte we read is written first within this call.
    float* h = (float*)d_ws;
    float* s = h + (size_t)NN * D;
    float* t = s + NN;

    // Zero the h' accumulator region (d_out poisoned 0xAA each timed call).
    hipMemsetAsync(d_out, 0, (size_t)NN * D * sizeof(float), stream);

    dim3 ggrid((NN + 63) / 64, 2);
    hipLaunchKernelGGL(gemm_xw, ggrid, dim3(256), 0, stream, x, W, h);
    hipLaunchKernelGGL(st_kernel, dim3((NN + 3) / 4), dim3(256), 0, stream, h, a, s, t);
    hipLaunchKernelGGL(edge_scatter, dim3(NE / 8), dim3(256), 0, stream,
                       edge, h, s, t, out_hp, out_ee);
    hipLaunchKernelGGL(elu_kernel, dim3(NN * D / 4 / 256), dim3(256), 0, stream, out_hp);
}

// Round 3
// 441.365 us; speedup vs baseline: 6.5250x; 6.5250x over previous
//
#include <hip/hip_runtime.h>
#include <math.h>

// Problem constants (from reference): N nodes, E edges, D features.
constexpr int NN = 100000;
constexpr int NE = 1600000;
constexpr int D  = 128;
constexpr float SLOPE = 0.2f;
constexpr int NBLK_SCAN = (NN + 255) / 256; // 391 blocks -> fits single-block scan of 512

// ---------------------------------------------------------------------------
// GEMM: h[N,128] = x[N,128] @ W[128,128], fp32 vector ALU (no fp32 MFMA on CDNA4).
// 64x64 tile, 256 threads, 64 KiB LDS -> 2 blocks/CU.
// ---------------------------------------------------------------------------
__global__ __launch_bounds__(256) void gemm_xw(const float* __restrict__ x,
                                               const float* __restrict__ W,
                                               float* __restrict__ h) {
    __shared__ float xsT[128 * 64];
    __shared__ float Ws [128 * 64];
    const int tid   = threadIdx.x;
    const int rbase = blockIdx.x * 64;
    const int cbase = blockIdx.y * 64;

#pragma unroll
    for (int i = 0; i < 8; ++i) {
        const int f = tid + i * 256;
        const int k = f >> 4;
        const int c = (f & 15) << 2;
        const float4 w = *reinterpret_cast<const float4*>(W + k * D + cbase + c);
        *reinterpret_cast<float4*>(Ws + k * 64 + c) = w;
    }
#pragma unroll
    for (int i = 0; i < 8; ++i) {
        const int f  = tid + i * 256;
        const int r  = f >> 5;
        const int c4 = f & 31;
        const int k0 = c4 << 2;
        float4 v = make_float4(0.f, 0.f, 0.f, 0.f);
        const int row = rbase + r;
        if (row < NN) v = *reinterpret_cast<const float4*>(x + (size_t)row * D + k0);
        const int rs = r ^ ((c4 & 7) << 2);
        xsT[(k0 + 0) * 64 + rs] = v.x;
        xsT[(k0 + 1) * 64 + rs] = v.y;
        xsT[(k0 + 2) * 64 + rs] = v.z;
        xsT[(k0 + 3) * 64 + rs] = v.w;
    }
    __syncthreads();

    const int r0 = (tid >> 4) << 2;
    const int c0 = (tid & 15) << 2;
    float acc[4][4] = {};
#pragma unroll 4
    for (int k = 0; k < 128; ++k) {
        const int sk = ((k >> 2) & 7) << 2;
        const float4 xv = *reinterpret_cast<const float4*>(xsT + k * 64 + (r0 ^ sk));
        const float4 wv = *reinterpret_cast<const float4*>(Ws  + k * 64 + c0);
        const float xr[4] = {xv.x, xv.y, xv.z, xv.w};
        const float wr[4] = {wv.x, wv.y, wv.z, wv.w};
#pragma unroll
        for (int i = 0; i < 4; ++i)
#pragma unroll
            for (int j = 0; j < 4; ++j)
                acc[i][j] = fmaf(xr[i], wr[j], acc[i][j]);
    }

#pragma unroll
    for (int i = 0; i < 4; ++i) {
        const int row = rbase + r0 + i;
        if (row < NN) {
            const float4 o = make_float4(acc[i][0], acc[i][1], acc[i][2], acc[i][3]);
            *reinterpret_cast<float4*>(h + (size_t)row * D + cbase + c0) = o;
        }
    }
}

// ---------------------------------------------------------------------------
// s[i] = h[i,:].a1 ; t[i] = h[i,:].a2. One wave per row, shuffle reduce.
// ---------------------------------------------------------------------------
__global__ __launch_bounds__(256) void st_kernel(const float* __restrict__ h,
                                                 const float* __restrict__ a,
                                                 float* __restrict__ s,
                                                 float* __restrict__ t) {
    const int row  = (int)((blockIdx.x * 256 + threadIdx.x) >> 6);
    const int lane = threadIdx.x & 63;
    if (row >= NN) return;
    const float2 hv = *reinterpret_cast<const float2*>(h + (size_t)row * D + lane * 2);
    const float2 a1 = *reinterpret_cast<const float2*>(a + lane * 2);
    const float2 a2 = *reinterpret_cast<const float2*>(a + D + lane * 2);
    float sp = hv.x * a1.x + hv.y * a1.y;
    float tp = hv.x * a2.x + hv.y * a2.y;
#pragma unroll
    for (int off = 32; off > 0; off >>= 1) {
        sp += __shfl_xor(sp, off);
        tp += __shfl_xor(tp, off);
    }
    if (lane == 0) { s[row] = sp; t[row] = tp; }
}

// ---------------------------------------------------------------------------
// CSR construction: histogram -> exclusive scan (3 kernels) -> slot scatter.
// ---------------------------------------------------------------------------
__global__ __launch_bounds__(256) void hist_kernel(const int* __restrict__ edge,
                                                   int* __restrict__ cnt) {
    const int e = blockIdx.x * 256 + threadIdx.x;
    if (e < NE) atomicAdd(&cnt[edge[e]], 1);
}

// Per-block exclusive scan of cnt -> partial; block totals -> bsum.
__global__ __launch_bounds__(256) void scan1(const int* __restrict__ cnt,
                                             int* __restrict__ partial,
                                             int* __restrict__ bsum) {
    __shared__ int sh[256];
    const int t = threadIdx.x;
    const int i = blockIdx.x * 256 + t;
    const int v = (i < NN) ? cnt[i] : 0;
    sh[t] = v;
    __syncthreads();
#pragma unroll
    for (int off = 1; off < 256; off <<= 1) {
        const int add = (t >= off) ? sh[t - off] : 0;
        __syncthreads();
        sh[t] += add;
        __syncthreads();
    }
    if (i < NN) partial[i] = sh[t] - v;        // exclusive within block
    if (t == 255) bsum[blockIdx.x] = sh[255];  // block total
}

// Single-block exclusive scan of the 391 block totals.
__global__ __launch_bounds__(512) void scan2(int* __restrict__ bsum) {
    __shared__ int sh[512];
    const int t = threadIdx.x;
    const int v = (t < NBLK_SCAN) ? bsum[t] : 0;
    sh[t] = v;
    __syncthreads();
#pragma unroll
    for (int off = 1; off < 512; off <<= 1) {
        const int add = (t >= off) ? sh[t - off] : 0;
        __syncthreads();
        sh[t] += add;
        __syncthreads();
    }
    if (t < NBLK_SCAN) bsum[t] = sh[t] - v;    // exclusive block offsets
}

__global__ __launch_bounds__(256) void scan3(const int* __restrict__ partial,
                                             const int* __restrict__ bsum,
                                             int* __restrict__ rs,
                                             int* __restrict__ cursor) {
    const int i = blockIdx.x * 256 + threadIdx.x;
    if (i < NN) {
        const int v = partial[i] + bsum[blockIdx.x];
        rs[i] = v;
        cursor[i] = v;
    }
}

// Per edge: compute ee (write coalesced in original order), allocate CSR slot,
// write packed (dst, ee). 1 thread/edge.
__global__ __launch_bounds__(256) void scatter_kernel(const int* __restrict__ edge,
                                                      const float* __restrict__ s,
                                                      const float* __restrict__ t,
                                                      int* __restrict__ cursor,
                                                      int2* __restrict__ sorted,
                                                      float* __restrict__ ee_out) {
    const int e = blockIdx.x * 256 + threadIdx.x;
    if (e >= NE) return;
    const int src = edge[e];
    const int dst = edge[NE + e];
    const float es = s[src] + t[dst];
    const float lr = es > 0.f ? es : SLOPE * es;
    const float ee = expf(-lr);
    ee_out[e] = ee;
    const int slot = atomicAdd(&cursor[src], 1);
    sorted[slot] = make_int2(dst, __float_as_int(ee));
}

// ---------------------------------------------------------------------------
// One wave per node: acc[128] = sum_j ee_j * h[dst_j,:], ELU, single write.
// Lane owns float2 of the row; pair loads are wave-uniform (broadcast, 1 tx).
// 4-edge unroll: 4 independent 8B gathers in flight per iteration (the loop
// is L2/L3-latency-bound; h = 51 MB is cache-resident).
// ---------------------------------------------------------------------------
__global__ __launch_bounds__(256) void gather_kernel(const int2* __restrict__ sorted,
                                                     const int* __restrict__ rs,
                                                     const int* __restrict__ cnt,
                                                     const float* __restrict__ h,
                                                     float* __restrict__ out) {
    const int node = blockIdx.x * 4 + (threadIdx.x >> 6);
    const int lane = threadIdx.x & 63;
    if (node >= NN) return;
    const int start = rs[node];
    const int n     = cnt[node];
    float2 acc = make_float2(0.f, 0.f);
    int j = 0;
    for (; j + 4 <= n; j += 4) {
        const int2 p0 = sorted[start + j];
        const int2 p1 = sorted[start + j + 1];
        const int2 p2 = sorted[start + j + 2];
        const int2 p3 = sorted[start + j + 3];
        const float2 h0 = *reinterpret_cast<const float2*>(h + (size_t)p0.x * D + lane * 2);
        const float2 h1 = *reinterpret_cast<const float2*>(h + (size_t)p1.x * D + lane * 2);
        const float2 h2 = *reinterpret_cast<const float2*>(h + (size_t)p2.x * D + lane * 2);
        const float2 h3 = *reinterpret_cast<const float2*>(h + (size_t)p3.x * D + lane * 2);
        const float e0 = __int_as_float(p0.y);
        const float e1 = __int_as_float(p1.y);
        const float e2 = __int_as_float(p2.y);
        const float e3 = __int_as_float(p3.y);
        acc.x = fmaf(e0, h0.x, acc.x); acc.y = fmaf(e0, h0.y, acc.y);
        acc.x = fmaf(e1, h1.x, acc.x); acc.y = fmaf(e1, h1.y, acc.y);
        acc.x = fmaf(e2, h2.x, acc.x); acc.y = fmaf(e2, h2.y, acc.y);
        acc.x = fmaf(e3, h3.x, acc.x); acc.y = fmaf(e3, h3.y, acc.y);
    }
    for (; j < n; ++j) {
        const int2 p0 = sorted[start + j];
        const float2 h0 = *reinterpret_cast<const float2*>(h + (size_t)p0.x * D + lane * 2);
        const float e0 = __int_as_float(p0.y);
        acc.x = fmaf(e0, h0.x, acc.x);
        acc.y = fmaf(e0, h0.y, acc.y);
    }
    // Fused ELU (zero-degree nodes write elu(0)=0, matching segment_sum + elu).
    acc.x = acc.x > 0.f ? acc.x : expm1f(acc.x);
    acc.y = acc.y > 0.f ? acc.y : expm1f(acc.y);
    *reinterpret_cast<float2*>(out + (size_t)node * D + lane * 2) = acc;
}

extern "C" void kernel_launch(void* const* d_in, const int* in_sizes, int n_in,
                              void* d_out, int out_size, void* d_ws, size_t ws_size,
                              hipStream_t stream) {
    const int*   edge = (const int*)d_in[0];   // [2,E] int32
    const float* x    = (const float*)d_in[1]; // [N,128]
    const float* W    = (const float*)d_in[2]; // [128,128]
    const float* a    = (const float*)d_in[3]; // [1,256]

    float* out_hp = (float*)d_out;                  // elu(h') [N,128]
    float* out_ee = (float*)d_out + (size_t)NN * D; // edge_e [E]

    // Workspace layout (~66 MB): every byte read is written first this call.
    float* h      = (float*)d_ws;                  // N*128 floats (51.2 MB)
    int2*  sorted = (int2*)(h + (size_t)NN * D);   // E pairs (12.8 MB)
    float* s      = (float*)(sorted + NE);
    float* t      = s + NN;
    int*   cnt    = (int*)(t + NN);
    int*   part   = cnt + NN;
    int*   rs     = part + NN;
    int*   cursor = rs + NN;
    int*   bsum   = cursor + NN;                   // 512 ints

    hipMemsetAsync(cnt, 0, (size_t)NN * sizeof(int), stream);

    dim3 ggrid((NN + 63) / 64, 2);
    hipLaunchKernelGGL(gemm_xw, ggrid, dim3(256), 0, stream, x, W, h);
    hipLaunchKernelGGL(st_kernel, dim3((NN + 3) / 4), dim3(256), 0, stream, h, a, s, t);
    hipLaunchKernelGGL(hist_kernel, dim3((NE + 255) / 256), dim3(256), 0, stream, edge, cnt);
    hipLaunchKernelGGL(scan1, dim3(NBLK_SCAN), dim3(256), 0, stream, cnt, part, bsum);
    hipLaunchKernelGGL(scan2, dim3(1), dim3(512), 0, stream, bsum);
    hipLaunchKernelGGL(scan3, dim3(NBLK_SCAN), dim3(256), 0, stream, part, bsum, rs, cursor);
    hipLaunchKernelGGL(scatter_kernel, dim3((NE + 255) / 256), dim3(256), 0, stream,
                       edge, s, t, cursor, sorted, out_ee);
    hipLaunchKernelGGL(gather_kernel, dim3((NN + 3) / 4), dim3(256), 0, stream,
                       sorted, rs, cnt, h, out_hp);
}

// Round 4
// 381.758 us; speedup vs baseline: 7.5439x; 1.1561x over previous
//
#include <hip/hip_runtime.h>
#include <hip/hip_fp16.h>
#include <math.h>

// Problem constants (from reference): N nodes, E edges, D features.
constexpr int NN = 100000;
constexpr int NE = 1600000;
constexpr int D  = 128;
constexpr float SLOPE = 0.2f;
constexpr int NBLK_SCAN = (NN + 255) / 256; // 391 -> fits single-block scan of 512

// ---------------------------------------------------------------------------
// Fused GEMM + s/t + fp16 pack:
//   acc = x[64rows] @ W[:,64cols] (fp32 vector ALU, LDS-tiled, R3-verified core)
//   h2[row, col] = fp16(acc)                      (only stored form of h)
//   s[row] += acc_slice . a1_slice ; t[row] += acc_slice . a2_slice (atomics)
// 64x64 tile, 256 threads, 64 KiB LDS -> 2 blocks/CU.
// ---------------------------------------------------------------------------
__global__ __launch_bounds__(256) void gemm_xw(const float* __restrict__ x,
                                               const float* __restrict__ W,
                                               const float* __restrict__ a,
                                               __half* __restrict__ h2,
                                               float* __restrict__ s,
                                               float* __restrict__ t) {
    __shared__ float xsT[128 * 64];
    __shared__ float Ws [128 * 64];
    const int tid   = threadIdx.x;
    const int rbase = blockIdx.x * 64;
    const int cbase = blockIdx.y * 64;

#pragma unroll
    for (int i = 0; i < 8; ++i) {
        const int f = tid + i * 256;
        const int k = f >> 4;
        const int c = (f & 15) << 2;
        const float4 w = *reinterpret_cast<const float4*>(W + k * D + cbase + c);
        *reinterpret_cast<float4*>(Ws + k * 64 + c) = w;
    }
#pragma unroll
    for (int i = 0; i < 8; ++i) {
        const int f  = tid + i * 256;
        const int r  = f >> 5;
        const int c4 = f & 31;
        const int k0 = c4 << 2;
        float4 v = make_float4(0.f, 0.f, 0.f, 0.f);
        const int row = rbase + r;
        if (row < NN) v = *reinterpret_cast<const float4*>(x + (size_t)row * D + k0);
        const int rs_ = r ^ ((c4 & 7) << 2);
        xsT[(k0 + 0) * 64 + rs_] = v.x;
        xsT[(k0 + 1) * 64 + rs_] = v.y;
        xsT[(k0 + 2) * 64 + rs_] = v.z;
        xsT[(k0 + 3) * 64 + rs_] = v.w;
    }
    __syncthreads();

    const int r0 = (tid >> 4) << 2;         // 4 rows/thread; 16 consecutive lanes share rows
    const int c0 = (tid & 15) << 2;         // 4 cols/thread
    float acc[4][4] = {};
#pragma unroll 4
    for (int k = 0; k < 128; ++k) {
        const int sk = ((k >> 2) & 7) << 2;
        const float4 xv = *reinterpret_cast<const float4*>(xsT + k * 64 + (r0 ^ sk));
        const float4 wv = *reinterpret_cast<const float4*>(Ws  + k * 64 + c0);
        const float xr[4] = {xv.x, xv.y, xv.z, xv.w};
        const float wr[4] = {wv.x, wv.y, wv.z, wv.w};
#pragma unroll
        for (int i = 0; i < 4; ++i)
#pragma unroll
            for (int j = 0; j < 4; ++j)
                acc[i][j] = fmaf(xr[i], wr[j], acc[i][j]);
    }

    // Epilogue 1: fp16 pack + store (8B per row-slice per thread).
#pragma unroll
    for (int i = 0; i < 4; ++i) {
        const int row = rbase + r0 + i;
        if (row < NN) {
            union { __half2 h[2]; uint2 u; } pk;
            pk.h[0] = __floats2half2_rn(acc[i][0], acc[i][1]);
            pk.h[1] = __floats2half2_rn(acc[i][2], acc[i][3]);
            *reinterpret_cast<uint2*>(h2 + (size_t)row * D + cbase + c0) = pk.u;
        }
    }

    // Epilogue 2: s,t partial dots over this block's 64-col slice.
    const float4 a1v = *reinterpret_cast<const float4*>(a + cbase + c0);
    const float4 a2v = *reinterpret_cast<const float4*>(a + D + cbase + c0);
    const float a1r[4] = {a1v.x, a1v.y, a1v.z, a1v.w};
    const float a2r[4] = {a2v.x, a2v.y, a2v.z, a2v.w};
    float sp[4], tp[4];
#pragma unroll
    for (int i = 0; i < 4; ++i) {
        sp[i] = 0.f; tp[i] = 0.f;
#pragma unroll
        for (int j = 0; j < 4; ++j) {
            sp[i] = fmaf(acc[i][j], a1r[j], sp[i]);
            tp[i] = fmaf(acc[i][j], a2r[j], tp[i]);
        }
    }
    // Reduce across the 16 lanes sharing these rows (lane-xor 1,2,4,8).
#pragma unroll
    for (int off = 1; off < 16; off <<= 1) {
#pragma unroll
        for (int i = 0; i < 4; ++i) {
            sp[i] += __shfl_xor(sp[i], off);
            tp[i] += __shfl_xor(tp[i], off);
        }
    }
    if ((tid & 15) == 0) {
#pragma unroll
        for (int i = 0; i < 4; ++i) {
            const int row = rbase + r0 + i;
            if (row < NN) {
                atomicAdd(&s[row], sp[i]);
                atomicAdd(&t[row], tp[i]);
            }
        }
    }
}

// ---------------------------------------------------------------------------
// CSR construction: histogram -> exclusive scan (3 kernels) -> slot scatter.
// ---------------------------------------------------------------------------
__global__ __launch_bounds__(256) void hist_kernel(const int* __restrict__ edge,
                                                   int* __restrict__ cnt) {
    const int e = blockIdx.x * 256 + threadIdx.x;
    if (e < NE) atomicAdd(&cnt[edge[e]], 1);
}

__global__ __launch_bounds__(256) void scan1(const int* __restrict__ cnt,
                                             int* __restrict__ partial,
                                             int* __restrict__ bsum) {
    __shared__ int sh[256];
    const int t = threadIdx.x;
    const int i = blockIdx.x * 256 + t;
    const int v = (i < NN) ? cnt[i] : 0;
    sh[t] = v;
    __syncthreads();
#pragma unroll
    for (int off = 1; off < 256; off <<= 1) {
        const int add = (t >= off) ? sh[t - off] : 0;
        __syncthreads();
        sh[t] += add;
        __syncthreads();
    }
    if (i < NN) partial[i] = sh[t] - v;
    if (t == 255) bsum[blockIdx.x] = sh[255];
}

__global__ __launch_bounds__(512) void scan2(int* __restrict__ bsum) {
    __shared__ int sh[512];
    const int t = threadIdx.x;
    const int v = (t < NBLK_SCAN) ? bsum[t] : 0;
    sh[t] = v;
    __syncthreads();
#pragma unroll
    for (int off = 1; off < 512; off <<= 1) {
        const int add = (t >= off) ? sh[t - off] : 0;
        __syncthreads();
        sh[t] += add;
        __syncthreads();
    }
    if (t < NBLK_SCAN) bsum[t] = sh[t] - v;
}

__global__ __launch_bounds__(256) void scan3(const int* __restrict__ partial,
                                             const int* __restrict__ bsum,
                                             int* __restrict__ rs,
                                             int* __restrict__ cursor) {
    const int i = blockIdx.x * 256 + threadIdx.x;
    if (i < NN) {
        const int v = partial[i] + bsum[blockIdx.x];
        rs[i] = v;
        cursor[i] = v;
    }
}

// Per edge: ee = exp(-leaky(s[src]+t[dst])) (coalesced write in edge order),
// CSR slot alloc, packed (dst, ee) write.
__global__ __launch_bounds__(256) void scatter_kernel(const int* __restrict__ edge,
                                                      const float* __restrict__ s,
                                                      const float* __restrict__ t,
                                                      int* __restrict__ cursor,
                                                      int2* __restrict__ sorted,
                                                      float* __restrict__ ee_out) {
    const int e = blockIdx.x * 256 + threadIdx.x;
    if (e >= NE) return;
    const int src = edge[e];
    const int dst = edge[NE + e];
    const float es = s[src] + t[dst];
    const float lr = es > 0.f ? es : SLOPE * es;
    const float ee = expf(-lr);
    ee_out[e] = ee;
    const int slot = atomicAdd(&cursor[src], 1);
    sorted[slot] = make_int2(dst, __float_as_int(ee));
}

// ---------------------------------------------------------------------------
// One wave per node, two edges per wave (half-wave split), fp16 h rows:
// lane hl in [0,32) loads 8B (4 halves) of a 256B row -> 4 edges in flight
// per half-wave. shfl_xor(32) combine, fused ELU, single float4 store.
// ---------------------------------------------------------------------------
__global__ __launch_bounds__(256) void gather_kernel(const int2* __restrict__ sorted,
                                                     const int* __restrict__ rs,
                                                     const int* __restrict__ cnt,
                                                     const __half* __restrict__ h2,
                                                     float* __restrict__ out) {
    const int node = blockIdx.x * 4 + (threadIdx.x >> 6);
    const int lane = threadIdx.x & 63;
    const int half = lane >> 5;
    const int hl   = lane & 31;
    if (node >= NN) return;
    const int start = rs[node];
    const int n     = cnt[node];
    float4 acc = make_float4(0.f, 0.f, 0.f, 0.f);

#define ROW_FMA(P, R) {                                                        \
        const float ee = __int_as_float((P).y);                                \
        const float2 f01 = __half22float2(*reinterpret_cast<const __half2*>(&(R).x)); \
        const float2 f23 = __half22float2(*reinterpret_cast<const __half2*>(&(R).y)); \
        acc.x = fmaf(ee, f01.x, acc.x); acc.y = fmaf(ee, f01.y, acc.y);        \
        acc.z = fmaf(ee, f23.x, acc.z); acc.w = fmaf(ee, f23.y, acc.w); }

    int j = 0;
    for (; j + 8 <= n; j += 8) {   // 8 edges: 4 per half-wave, all loads independent
        const int2 p0 = sorted[start + j + 0 + half];
        const int2 p1 = sorted[start + j + 2 + half];
        const int2 p2 = sorted[start + j + 4 + half];
        const int2 p3 = sorted[start + j + 6 + half];
        const uint2 r0 = *reinterpret_cast<const uint2*>(h2 + (size_t)p0.x * D + hl * 4);
        const uint2 r1 = *reinterpret_cast<const uint2*>(h2 + (size_t)p1.x * D + hl * 4);
        const uint2 r2 = *reinterpret_cast<const uint2*>(h2 + (size_t)p2.x * D + hl * 4);
        const uint2 r3 = *reinterpret_cast<const uint2*>(h2 + (size_t)p3.x * D + hl * 4);
        ROW_FMA(p0, r0) ROW_FMA(p1, r1) ROW_FMA(p2, r2) ROW_FMA(p3, r3)
    }
    for (; j + 2 <= n; j += 2) {   // one edge per half-wave
        const int2 p0 = sorted[start + j + half];
        const uint2 r0 = *reinterpret_cast<const uint2*>(h2 + (size_t)p0.x * D + hl * 4);
        ROW_FMA(p0, r0)
    }
    if (j < n && half == 0) {      // odd tail: half 0 only
        const int2 p0 = sorted[start + j];
        const uint2 r0 = *reinterpret_cast<const uint2*>(h2 + (size_t)p0.x * D + hl * 4);
        ROW_FMA(p0, r0)
    }
#undef ROW_FMA

    acc.x += __shfl_xor(acc.x, 32);
    acc.y += __shfl_xor(acc.y, 32);
    acc.z += __shfl_xor(acc.z, 32);
    acc.w += __shfl_xor(acc.w, 32);
    if (half == 0) {
        acc.x = acc.x > 0.f ? acc.x : expm1f(acc.x);
        acc.y = acc.y > 0.f ? acc.y : expm1f(acc.y);
        acc.z = acc.z > 0.f ? acc.z : expm1f(acc.z);
        acc.w = acc.w > 0.f ? acc.w : expm1f(acc.w);
        *reinterpret_cast<float4*>(out + (size_t)node * D + hl * 4) = acc;
    }
}

extern "C" void kernel_launch(void* const* d_in, const int* in_sizes, int n_in,
                              void* d_out, int out_size, void* d_ws, size_t ws_size,
                              hipStream_t stream) {
    const int*   edge = (const int*)d_in[0];   // [2,E] int32
    const float* x    = (const float*)d_in[1]; // [N,128]
    const float* W    = (const float*)d_in[2]; // [128,128]
    const float* a    = (const float*)d_in[3]; // [1,256]

    float* out_hp = (float*)d_out;                  // elu(h') [N,128]
    float* out_ee = (float*)d_out + (size_t)NN * D; // edge_e [E]

    // Workspace (~41 MB). Every byte read is written first within this call.
    __half* h2     = (__half*)d_ws;                    // N*128 fp16 (25.6 MB)
    int2*   sorted = (int2*)(h2 + (size_t)NN * D);     // E pairs (12.8 MB)
    float*  s      = (float*)(sorted + NE);            // [s|t|cnt] contiguous, zeroed
    float*  t      = s + NN;
    int*    cnt    = (int*)(t + NN);
    int*    part   = cnt + NN;
    int*    rs     = part + NN;
    int*    cursor = rs + NN;
    int*    bsum   = cursor + NN;                      // 512 ints

    hipMemsetAsync(s, 0, 3 * (size_t)NN * sizeof(float), stream); // s, t, cnt

    dim3 ggrid((NN + 63) / 64, 2);
    hipLaunchKernelGGL(gemm_xw, ggrid, dim3(256), 0, stream, x, W, a, h2, s, t);
    hipLaunchKernelGGL(hist_kernel, dim3((NE + 255) / 256), dim3(256), 0, stream, edge, cnt);
    hipLaunchKernelGGL(scan1, dim3(NBLK_SCAN), dim3(256), 0, stream, cnt, part, bsum);
    hipLaunchKernelGGL(scan2, dim3(1), dim3(512), 0, stream, bsum);
    hipLaunchKernelGGL(scan3, dim3(NBLK_SCAN), dim3(256), 0, stream, part, bsum, rs, cursor);
    hipLaunchKernelGGL(scatter_kernel, dim3((NE + 255) / 256), dim3(256), 0, stream,
                       edge, s, t, cursor, sorted, out_ee);
    hipLaunchKernelGGL(gather_kernel, dim3((NN + 3) / 4), dim3(256), 0, stream,
                       sorted, rs, cnt, h2, out_hp);
}